// Round 6
// baseline (252.686 us; speedup 1.0000x reference)
//
#include <hip/hip_runtime.h>
#include <hip/hip_bf16.h>
#include <cstdint>
#include <math.h>

#define B_    2
#define S_    2048
#define DIM_  1536
#define H_    12
#define HD_   128
#define TRI_  4608   // 3*DIM
#define M_    4096   // B*S

typedef __attribute__((ext_vector_type(8))) __bf16 bf16x8;
typedef __attribute__((ext_vector_type(4))) __bf16 bf16x4;
typedef __attribute__((ext_vector_type(4))) float  floatx4;

typedef __attribute__((address_space(3))) uint8_t       lds_u8;
typedef const __attribute__((address_space(1))) uint8_t glob_u8;

// ---------------- prep: W1/W2 transpose+cvt, x cvt, out zero — one launch
// sections: [0,T1) W1 tiles | [T1,T1+T2) W2 tiles | cvt 6144 | zero 6144
__global__ __launch_bounds__(256) void prep(const float* __restrict__ W1,
                                            __bf16* __restrict__ O1,
                                            const float* __restrict__ W2,
                                            __bf16* __restrict__ O2,
                                            const float* __restrict__ x,
                                            __bf16* __restrict__ x_bf,
                                            float* __restrict__ outz) {
    const int T1 = (TRI_ / 64) * (DIM_ / 64);   // 1728
    const int T2 = (DIM_ / 64) * (DIM_ / 64);   // 576
    const int NC = (M_ * DIM_) / 1024;          // 6144
    int blk = blockIdx.x;
    const int t = threadIdx.x;

    if (blk >= T1 + T2) {
        blk -= T1 + T2;
        if (blk < NC) {                         // cvt x -> bf16
            int i = blk * 256 + t;
            float4 v = ((const float4*)x)[i];
            bf16x4 o;
            o.x = (__bf16)v.x; o.y = (__bf16)v.y; o.z = (__bf16)v.z; o.w = (__bf16)v.w;
            *(bf16x4*)(x_bf + (size_t)i * 4) = o;
        } else {                                // zero out-buffer
            blk -= NC;
            int i = blk * 256 + t;
            ((float4*)outz)[i] = make_float4(0.f, 0.f, 0.f, 0.f);
        }
        return;
    }

    const float* in; __bf16* out; int R, C, c0, r0;
    if (blk < T1) {
        in = W1; out = O1; R = DIM_; C = TRI_;
        c0 = (blk % (TRI_ / 64)) * 64; r0 = (blk / (TRI_ / 64)) * 64;
    } else {
        blk -= T1;
        in = W2; out = O2; R = DIM_; C = DIM_;
        c0 = (blk % (DIM_ / 64)) * 64; r0 = (blk / (DIM_ / 64)) * 64;
    }
    __shared__ float tile[64][65];
    const int c4 = t & 15, r = t >> 4;
    #pragma unroll
    for (int i = 0; i < 64; i += 16) {
        float4 v = *(const float4*)&in[(size_t)(r0 + r + i) * C + c0 + c4 * 4];
        tile[r + i][c4 * 4 + 0] = v.x;
        tile[r + i][c4 * 4 + 1] = v.y;
        tile[r + i][c4 * 4 + 2] = v.z;
        tile[r + i][c4 * 4 + 3] = v.w;
    }
    __syncthreads();
    const int cc = t >> 2, ch = t & 3;
    #pragma unroll
    for (int cho = 0; cho < 8; cho += 4) {
        int chh = ch + cho;
        bf16x8 o;
        #pragma unroll
        for (int k = 0; k < 8; ++k) o[k] = (__bf16)tile[chh * 8 + k][cc];
        *(bf16x8*)&out[(size_t)(c0 + cc) * R + r0 + chh * 8] = o;
    }
}

// ------------------------------- QKV GEMM 128x192, BK=64, single-buffer 2-barrier
// 4 waves each 64x96 (4x6 frags); 3-bit XOR swizzle — verified 0 bank conflicts
__global__ __launch_bounds__(256, 3) void gemm_qkv(const __bf16* __restrict__ A,
                                                   const __bf16* __restrict__ Bt,
                                                   const float*  __restrict__ bias,
                                                   __bf16* __restrict__ Cout,
                                                   int Mdim, int Ndim, int Kdim) {
    __shared__ __align__(16) __bf16 sA[128 * 64];   // 16 KB
    __shared__ __align__(16) __bf16 sB[192 * 64];   // 24 KB

    const int ntiles = Ndim / 192;
    const int tile_n = blockIdx.x % ntiles;
    const int tile_m = blockIdx.x / ntiles;
    const int m0 = tile_m << 7, n0 = tile_n * 192;

    const int tid  = threadIdx.x;
    const int lane = tid & 63;
    const int wave = tid >> 6;
    const int wm = (wave >> 1) * 64;
    const int wn = (wave & 1) * 96;

    floatx4 acc[4][6] = {};

    const int lr8 = lane >> 3;
    const int swz = (((lane & 7) ^ lr8) * 8);
    const int row  = lane & 15;
    const int quad = lane >> 4;
    const int xr   = row & 7;

    for (int k0 = 0; k0 < Kdim; k0 += 64) {
        #pragma unroll
        for (int c = 0; c < 4; ++c) {
            int r0 = wave * 32 + c * 8;
            const __bf16* ga = A + (size_t)(m0 + r0 + lr8) * Kdim + k0 + swz;
            __builtin_amdgcn_global_load_lds((glob_u8*)ga, (lds_u8*)&sA[r0 * 64], 16, 0, 0);
        }
        #pragma unroll
        for (int c = 0; c < 6; ++c) {
            int r0 = wave * 48 + c * 8;
            const __bf16* gb = Bt + (size_t)(n0 + r0 + lr8) * Kdim + k0 + swz;
            __builtin_amdgcn_global_load_lds((glob_u8*)gb, (lds_u8*)&sB[r0 * 64], 16, 0, 0);
        }
        __syncthreads();

        #pragma unroll
        for (int ks = 0; ks < 2; ++ks) {
            const int ko = ((ks * 4 + quad) ^ xr) * 8;
            bf16x8 af[4], bfr[6];
            #pragma unroll
            for (int i = 0; i < 4; ++i)
                af[i] = *(const bf16x8*)&sA[(wm + i * 16 + row) * 64 + ko];
            #pragma unroll
            for (int j = 0; j < 6; ++j)
                bfr[j] = *(const bf16x8*)&sB[(wn + j * 16 + row) * 64 + ko];
            #pragma unroll
            for (int i = 0; i < 4; ++i)
                #pragma unroll
                for (int j = 0; j < 6; ++j)
                    acc[i][j] = __builtin_amdgcn_mfma_f32_16x16x32_bf16(af[i], bfr[j], acc[i][j], 0, 0, 0);
        }
        __syncthreads();
    }

    #pragma unroll
    for (int j = 0; j < 6; ++j) {
        int gc = n0 + wn + j * 16 + row;
        float bv = bias[gc];
        #pragma unroll
        for (int i = 0; i < 4; ++i) {
            #pragma unroll
            for (int r = 0; r < 4; ++r) {
                int gr = m0 + wm + i * 16 + quad * 4 + r;
                Cout[(size_t)gr * Ndim + gc] = (__bf16)(acc[i][j][r] + bv);
            }
        }
    }
}

// ------------- out GEMM: split-K=2, 128x128 tile, BK=64, 4 waves, atomic epilogue
// slice 0 handles k[0,768) + bias; slice 1 handles k[768,1536). Out pre-zeroed.
// f32 atomicAdd is order-independent for 2 addends -> deterministic.
__global__ __launch_bounds__(256, 3) void gemm_out(const __bf16* __restrict__ A,
                                                   const __bf16* __restrict__ Bt,
                                                   const float*  __restrict__ bias,
                                                   float* __restrict__ Cout,
                                                   int Mdim, int Ndim, int Kdim) {
    __shared__ __align__(16) __bf16 sA[128 * 64];   // 16 KB
    __shared__ __align__(16) __bf16 sB[128 * 64];   // 16 KB

    const int ntiles = Ndim >> 7;                   // 12
    const int half = (Mdim >> 7) * ntiles;          // 384
    int idx = blockIdx.x;
    const int slice = idx >= half;
    if (slice) idx -= half;
    const int tile_n = idx % ntiles;
    const int tile_m = idx / ntiles;
    const int m0 = tile_m << 7, n0 = tile_n << 7;
    const int kbeg = slice ? (Kdim >> 1) : 0;
    const int kend = kbeg + (Kdim >> 1);

    const int tid  = threadIdx.x;
    const int lane = tid & 63;
    const int wave = tid >> 6;
    const int wm = (wave >> 1) * 64;
    const int wn = (wave & 1) * 64;

    floatx4 acc[4][4] = {};

    const int lr8 = lane >> 3;
    const int swz = (((lane & 7) ^ lr8) * 8);
    const int row  = lane & 15;
    const int quad = lane >> 4;
    const int xr   = row & 7;

    for (int k0 = kbeg; k0 < kend; k0 += 64) {
        #pragma unroll
        for (int c = 0; c < 4; ++c) {
            int r0 = wave * 32 + c * 8;
            const __bf16* ga = A + (size_t)(m0 + r0 + lr8) * Kdim + k0 + swz;
            __builtin_amdgcn_global_load_lds((glob_u8*)ga, (lds_u8*)&sA[r0 * 64], 16, 0, 0);
            const __bf16* gb = Bt + (size_t)(n0 + r0 + lr8) * Kdim + k0 + swz;
            __builtin_amdgcn_global_load_lds((glob_u8*)gb, (lds_u8*)&sB[r0 * 64], 16, 0, 0);
        }
        __syncthreads();

        #pragma unroll
        for (int ks = 0; ks < 2; ++ks) {
            const int ko = ((ks * 4 + quad) ^ xr) * 8;
            bf16x8 af[4], bfr[4];
            #pragma unroll
            for (int i = 0; i < 4; ++i) {
                af[i]  = *(const bf16x8*)&sA[(wm + i * 16 + row) * 64 + ko];
                bfr[i] = *(const bf16x8*)&sB[(wn + i * 16 + row) * 64 + ko];
            }
            #pragma unroll
            for (int i = 0; i < 4; ++i)
                #pragma unroll
                for (int j = 0; j < 4; ++j)
                    acc[i][j] = __builtin_amdgcn_mfma_f32_16x16x32_bf16(af[i], bfr[j], acc[i][j], 0, 0, 0);
        }
        __syncthreads();
    }

    #pragma unroll
    for (int j = 0; j < 4; ++j) {
        int gc = n0 + wn + j * 16 + row;
        float bv = slice ? 0.f : bias[gc];
        #pragma unroll
        for (int i = 0; i < 4; ++i) {
            #pragma unroll
            for (int r = 0; r < 4; ++r) {
                int gr = m0 + wm + i * 16 + quad * 4 + r;
                atomicAdd(&Cout[(size_t)gr * Ndim + gc], acc[i][j][r] + bv);
            }
        }
    }
}

// ------------------------------------------------------------------ anchor attention
__global__ __launch_bounds__(192) void anchor_attn(const __bf16* __restrict__ qkv,
                                                   const float* __restrict__ group_scale,
                                                   __bf16* __restrict__ attn_out) {
    const int bs = blockIdx.x;
    const int b  = bs >> 11;
    const int s  = bs & 2047;
    const int t  = threadIdx.x;
    const int h  = t >> 4;
    const int tt = t & 15;
    const int d0 = tt * 8;

    float g0 = group_scale[0], g1 = group_scale[1], g2 = group_scale[2];
    float gm = fmaxf(g0, fmaxf(g1, g2));
    float e0 = __expf(g0 - gm), e1 = __expf(g1 - gm), e2 = __expf(g2 - gm);
    float ls = __logf(e0 + e1 + e2);
    float lw0 = g0 - gm - ls, lw1 = g1 - gm - ls, lw2 = g2 - gm - ls;

    const size_t rowbase = (size_t)(b * S_ + s) * TRI_ + h * HD_ + d0;
    bf16x8 qv = *(const bf16x8*)(qkv + rowbase);
    float q[8];
    #pragma unroll
    for (int k = 0; k < 8; ++k) q[k] = (float)qv[k];

    int idxs[12];
    const int offs[10] = {-3, -2, -1, 1, 2, 3, -10, -5, 5, 10};
    #pragma unroll
    for (int a = 0; a < 10; ++a) {
        int tgt = s + offs[a];
        idxs[a] = min(max(tgt, 0), S_ - 1);
    }
    idxs[10] = 0; idxs[11] = S_ - 1;

    const float scale = 0.08838834764831845f;
    float p[12];
    float mx = -1e30f;
    #pragma unroll
    for (int a = 0; a < 12; ++a) {
        const __bf16* kp = qkv + (size_t)(b * S_ + idxs[a]) * TRI_ + DIM_ + h * HD_ + d0;
        bf16x8 kv = *(const bf16x8*)kp;
        float d = 0.f;
        #pragma unroll
        for (int k = 0; k < 8; ++k) d += q[k] * (float)kv[k];
        d += __shfl_xor(d, 1); d += __shfl_xor(d, 2);
        d += __shfl_xor(d, 4); d += __shfl_xor(d, 8);
        float sc = d * scale + (a < 6 ? lw0 : (a < 10 ? lw1 : lw2));
        p[a] = sc;
        mx = fmaxf(mx, sc);
    }
    float l = 0.f;
    #pragma unroll
    for (int a = 0; a < 12; ++a) { p[a] = __expf(p[a] - mx); l += p[a]; }
    float inv = 1.0f / l;

    float o[8] = {};
    #pragma unroll
    for (int a = 0; a < 12; ++a) {
        const __bf16* vp = qkv + (size_t)(b * S_ + idxs[a]) * TRI_ + 2 * DIM_ + h * HD_ + d0;
        bf16x8 vv = *(const bf16x8*)vp;
        #pragma unroll
        for (int k = 0; k < 8; ++k) o[k] += p[a] * (float)vv[k];
    }
    bf16x8 ov;
    #pragma unroll
    for (int k = 0; k < 8; ++k) ov[k] = (__bf16)(o[k] * inv);
    *(bf16x8*)(attn_out + (size_t)(b * S_ + s) * DIM_ + h * HD_ + d0) = ov;
}

// ----------------------------------------------------------------------- launcher
extern "C" void kernel_launch(void* const* d_in, const int* in_sizes, int n_in,
                              void* d_out, int out_size, void* d_ws, size_t ws_size,
                              hipStream_t stream) {
    const float* x    = (const float*)d_in[0];
    const float* Wqkv = (const float*)d_in[1];
    const float* bqkv = (const float*)d_in[2];
    const float* Wout = (const float*)d_in[3];
    const float* bout = (const float*)d_in[4];
    const float* gsc  = (const float*)d_in[5];
    float* out = (float*)d_out;

    char* ws = (char*)d_ws;
    __bf16* x_bf   = (__bf16*)(ws);
    __bf16* WqkvT  = (__bf16*)(ws + 12582912);
    __bf16* WoutT  = (__bf16*)(ws + 12582912 + 14155776);
    __bf16* qkv    = (__bf16*)(ws + 12582912 + 14155776 + 4718592);
    __bf16* attn   = (__bf16*)(ws + 12582912 + 14155776 + 4718592 + 37748736);

    // prep: transposes + cvt + out zero-init (one launch)
    {
        int nblk = (TRI_ / 64) * (DIM_ / 64) + (DIM_ / 64) * (DIM_ / 64)
                 + (M_ * DIM_) / 1024 + (M_ * DIM_) / 1024;
        prep<<<nblk, 256, 0, stream>>>(Wqkv, WqkvT, Wout, WoutT, x, x_bf, out);
    }

    // QKV GEMM: 128x192 tiles -> 768 blocks (3.0/CU)
    gemm_qkv<<<(M_ / 128) * (TRI_ / 192), 256, 0, stream>>>(
        x_bf, WqkvT, bqkv, qkv, M_, TRI_, DIM_);

    // anchor attention
    anchor_attn<<<B_ * S_, 192, 0, stream>>>(qkv, gsc, attn);

    // out GEMM: split-K=2, 128x128 tiles -> 768 blocks (3.0/CU), atomic epilogue
    gemm_out<<<2 * (M_ / 128) * (DIM_ / 128), 256, 0, stream>>>(
        attn, WoutT, bout, out, M_, DIM_, DIM_);
}

// Round 7
// 230.090 us; speedup vs baseline: 1.0982x; 1.0982x over previous
//
#include <hip/hip_runtime.h>
#include <hip/hip_bf16.h>
#include <cstdint>
#include <math.h>

#define B_    2
#define S_    2048
#define DIM_  1536
#define H_    12
#define HD_   128
#define TRI_  4608   // 3*DIM
#define M_    4096   // B*S

typedef __attribute__((ext_vector_type(8))) __bf16 bf16x8;
typedef __attribute__((ext_vector_type(4))) __bf16 bf16x4;
typedef __attribute__((ext_vector_type(4))) float  floatx4;

typedef __attribute__((address_space(3))) uint8_t       lds_u8;
typedef const __attribute__((address_space(1))) uint8_t glob_u8;

// ---------------- prep: W1/W2 transpose+cvt, x cvt — one launch
__global__ __launch_bounds__(256) void prep(const float* __restrict__ W1,
                                            __bf16* __restrict__ O1,
                                            const float* __restrict__ W2,
                                            __bf16* __restrict__ O2,
                                            const float* __restrict__ x,
                                            __bf16* __restrict__ x_bf) {
    const int T1 = (TRI_ / 64) * (DIM_ / 64);   // 1728
    const int T2 = (DIM_ / 64) * (DIM_ / 64);   // 576
    int blk = blockIdx.x;
    const int t = threadIdx.x;

    if (blk >= T1 + T2) {                       // cvt x -> bf16
        blk -= T1 + T2;
        int i = blk * 256 + t;
        float4 v = ((const float4*)x)[i];
        bf16x4 o;
        o.x = (__bf16)v.x; o.y = (__bf16)v.y; o.z = (__bf16)v.z; o.w = (__bf16)v.w;
        *(bf16x4*)(x_bf + (size_t)i * 4) = o;
        return;
    }

    const float* in; __bf16* out; int R, C, c0, r0;
    if (blk < T1) {
        in = W1; out = O1; R = DIM_; C = TRI_;
        c0 = (blk % (TRI_ / 64)) * 64; r0 = (blk / (TRI_ / 64)) * 64;
    } else {
        blk -= T1;
        in = W2; out = O2; R = DIM_; C = DIM_;
        c0 = (blk % (DIM_ / 64)) * 64; r0 = (blk / (DIM_ / 64)) * 64;
    }
    __shared__ float tile[64][65];
    const int c4 = t & 15, r = t >> 4;
    #pragma unroll
    for (int i = 0; i < 64; i += 16) {
        float4 v = *(const float4*)&in[(size_t)(r0 + r + i) * C + c0 + c4 * 4];
        tile[r + i][c4 * 4 + 0] = v.x;
        tile[r + i][c4 * 4 + 1] = v.y;
        tile[r + i][c4 * 4 + 2] = v.z;
        tile[r + i][c4 * 4 + 3] = v.w;
    }
    __syncthreads();
    const int cc = t >> 2, ch = t & 3;
    #pragma unroll
    for (int cho = 0; cho < 8; cho += 4) {
        int chh = ch + cho;
        bf16x8 o;
        #pragma unroll
        for (int k = 0; k < 8; ++k) o[k] = (__bf16)tile[chh * 8 + k][cc];
        *(bf16x8*)&out[(size_t)(c0 + cc) * R + r0 + chh * 8] = o;
    }
}

// ------------------------------- QKV GEMM 128x192, BK=64, single-buffer 2-barrier
// 4 waves each 64x96; 3-bit XOR swizzle — measured 0 bank conflicts, ~950 TF
__global__ __launch_bounds__(256, 3) void gemm_qkv(const __bf16* __restrict__ A,
                                                   const __bf16* __restrict__ Bt,
                                                   const float*  __restrict__ bias,
                                                   __bf16* __restrict__ Cout,
                                                   int Mdim, int Ndim, int Kdim) {
    __shared__ __align__(16) __bf16 sA[128 * 64];   // 16 KB
    __shared__ __align__(16) __bf16 sB[192 * 64];   // 24 KB

    const int ntiles = Ndim / 192;
    const int tile_n = blockIdx.x % ntiles;
    const int tile_m = blockIdx.x / ntiles;
    const int m0 = tile_m << 7, n0 = tile_n * 192;

    const int tid  = threadIdx.x;
    const int lane = tid & 63;
    const int wave = tid >> 6;
    const int wm = (wave >> 1) * 64;
    const int wn = (wave & 1) * 96;

    floatx4 acc[4][6] = {};

    const int lr8 = lane >> 3;
    const int swz = (((lane & 7) ^ lr8) * 8);
    const int row  = lane & 15;
    const int quad = lane >> 4;
    const int xr   = row & 7;

    for (int k0 = 0; k0 < Kdim; k0 += 64) {
        #pragma unroll
        for (int c = 0; c < 4; ++c) {
            int r0 = wave * 32 + c * 8;
            const __bf16* ga = A + (size_t)(m0 + r0 + lr8) * Kdim + k0 + swz;
            __builtin_amdgcn_global_load_lds((glob_u8*)ga, (lds_u8*)&sA[r0 * 64], 16, 0, 0);
        }
        #pragma unroll
        for (int c = 0; c < 6; ++c) {
            int r0 = wave * 48 + c * 8;
            const __bf16* gb = Bt + (size_t)(n0 + r0 + lr8) * Kdim + k0 + swz;
            __builtin_amdgcn_global_load_lds((glob_u8*)gb, (lds_u8*)&sB[r0 * 64], 16, 0, 0);
        }
        __syncthreads();

        #pragma unroll
        for (int ks = 0; ks < 2; ++ks) {
            const int ko = ((ks * 4 + quad) ^ xr) * 8;
            bf16x8 af[4], bfr[6];
            #pragma unroll
            for (int i = 0; i < 4; ++i)
                af[i] = *(const bf16x8*)&sA[(wm + i * 16 + row) * 64 + ko];
            #pragma unroll
            for (int j = 0; j < 6; ++j)
                bfr[j] = *(const bf16x8*)&sB[(wn + j * 16 + row) * 64 + ko];
            #pragma unroll
            for (int i = 0; i < 4; ++i)
                #pragma unroll
                for (int j = 0; j < 6; ++j)
                    acc[i][j] = __builtin_amdgcn_mfma_f32_16x16x32_bf16(af[i], bfr[j], acc[i][j], 0, 0, 0);
        }
        __syncthreads();
    }

    #pragma unroll
    for (int j = 0; j < 6; ++j) {
        int gc = n0 + wn + j * 16 + row;
        float bv = bias[gc];
        #pragma unroll
        for (int i = 0; i < 4; ++i) {
            #pragma unroll
            for (int r = 0; r < 4; ++r) {
                int gr = m0 + wm + i * 16 + quad * 4 + r;
                Cout[(size_t)gr * Ndim + gc] = (__bf16)(acc[i][j][r] + bv);
            }
        }
    }
}

// ---------------- out GEMM: 128x128 tile, BK=128, single-buffer, 12 K-iters
// 64 KB LDS; 4-bit XOR swizzle for 256B rows (16 chunks of 16B)
__global__ __launch_bounds__(256) void gemm_out(const __bf16* __restrict__ A,
                                                const __bf16* __restrict__ Bt,
                                                const float*  __restrict__ bias,
                                                float* __restrict__ Cout,
                                                int Mdim, int Ndim, int Kdim) {
    __shared__ __align__(16) __bf16 sA[128 * 128];   // 32 KB
    __shared__ __align__(16) __bf16 sB[128 * 128];   // 32 KB

    const int ntiles = Ndim >> 7;
    const int tile_n = blockIdx.x % ntiles;
    const int tile_m = blockIdx.x / ntiles;
    const int m0 = tile_m << 7, n0 = tile_n << 7;

    const int tid  = threadIdx.x;
    const int lane = tid & 63;
    const int wave = tid >> 6;
    const int wm = (wave >> 1) * 64;
    const int wn = (wave & 1) * 64;

    floatx4 acc[4][4] = {};

    const int lr4 = lane >> 4;          // 0..3 : row within 4-row DMA group
    const int lc  = lane & 15;          // 16B-chunk slot
    int swz[4];
    #pragma unroll
    for (int v = 0; v < 4; ++v) swz[v] = (lc ^ (v * 4 + lr4)) * 8;  // elems

    const int row  = lane & 15;
    const int quad = lane >> 4;

    for (int k0 = 0; k0 < Kdim; k0 += 128) {
        #pragma unroll
        for (int c = 0; c < 8; ++c) {
            int r0 = wave * 32 + c * 4;          // wave-uniform base row
            const __bf16* ga = A + (size_t)(m0 + r0 + lr4) * Kdim + k0 + swz[c & 3];
            __builtin_amdgcn_global_load_lds((glob_u8*)ga, (lds_u8*)&sA[r0 * 128], 16, 0, 0);
            const __bf16* gb = Bt + (size_t)(n0 + r0 + lr4) * Kdim + k0 + swz[c & 3];
            __builtin_amdgcn_global_load_lds((glob_u8*)gb, (lds_u8*)&sB[r0 * 128], 16, 0, 0);
        }
        __syncthreads();

        #pragma unroll
        for (int ks = 0; ks < 4; ++ks) {
            const int ck = ((ks * 4 + quad) ^ row) * 8;
            bf16x8 af[4], bfr[4];
            #pragma unroll
            for (int i = 0; i < 4; ++i) {
                af[i]  = *(const bf16x8*)&sA[(wm + i * 16 + row) * 128 + ck];
                bfr[i] = *(const bf16x8*)&sB[(wn + i * 16 + row) * 128 + ck];
            }
            #pragma unroll
            for (int i = 0; i < 4; ++i)
                #pragma unroll
                for (int j = 0; j < 4; ++j)
                    acc[i][j] = __builtin_amdgcn_mfma_f32_16x16x32_bf16(af[i], bfr[j], acc[i][j], 0, 0, 0);
        }
        __syncthreads();
    }

    #pragma unroll
    for (int j = 0; j < 4; ++j) {
        int gc = n0 + wn + j * 16 + row;
        float bv = bias[gc];
        #pragma unroll
        for (int i = 0; i < 4; ++i) {
            #pragma unroll
            for (int r = 0; r < 4; ++r) {
                int gr = m0 + wm + i * 16 + quad * 4 + r;
                Cout[(size_t)gr * Ndim + gc] = acc[i][j][r] + bv;
            }
        }
    }
}

// ------------------------------------------------------------------ anchor attention
__global__ __launch_bounds__(192) void anchor_attn(const __bf16* __restrict__ qkv,
                                                   const float* __restrict__ group_scale,
                                                   __bf16* __restrict__ attn_out) {
    const int bs = blockIdx.x;
    const int b  = bs >> 11;
    const int s  = bs & 2047;
    const int t  = threadIdx.x;
    const int h  = t >> 4;
    const int tt = t & 15;
    const int d0 = tt * 8;

    float g0 = group_scale[0], g1 = group_scale[1], g2 = group_scale[2];
    float gm = fmaxf(g0, fmaxf(g1, g2));
    float e0 = __expf(g0 - gm), e1 = __expf(g1 - gm), e2 = __expf(g2 - gm);
    float ls = __logf(e0 + e1 + e2);
    float lw0 = g0 - gm - ls, lw1 = g1 - gm - ls, lw2 = g2 - gm - ls;

    const size_t rowbase = (size_t)(b * S_ + s) * TRI_ + h * HD_ + d0;
    bf16x8 qv = *(const bf16x8*)(qkv + rowbase);
    float q[8];
    #pragma unroll
    for (int k = 0; k < 8; ++k) q[k] = (float)qv[k];

    int idxs[12];
    const int offs[10] = {-3, -2, -1, 1, 2, 3, -10, -5, 5, 10};
    #pragma unroll
    for (int a = 0; a < 10; ++a) {
        int tgt = s + offs[a];
        idxs[a] = min(max(tgt, 0), S_ - 1);
    }
    idxs[10] = 0; idxs[11] = S_ - 1;

    const float scale = 0.08838834764831845f;
    float p[12];
    float mx = -1e30f;
    #pragma unroll
    for (int a = 0; a < 12; ++a) {
        const __bf16* kp = qkv + (size_t)(b * S_ + idxs[a]) * TRI_ + DIM_ + h * HD_ + d0;
        bf16x8 kv = *(const bf16x8*)kp;
        float d = 0.f;
        #pragma unroll
        for (int k = 0; k < 8; ++k) d += q[k] * (float)kv[k];
        d += __shfl_xor(d, 1); d += __shfl_xor(d, 2);
        d += __shfl_xor(d, 4); d += __shfl_xor(d, 8);
        float sc = d * scale + (a < 6 ? lw0 : (a < 10 ? lw1 : lw2));
        p[a] = sc;
        mx = fmaxf(mx, sc);
    }
    float l = 0.f;
    #pragma unroll
    for (int a = 0; a < 12; ++a) { p[a] = __expf(p[a] - mx); l += p[a]; }
    float inv = 1.0f / l;

    float o[8] = {};
    #pragma unroll
    for (int a = 0; a < 12; ++a) {
        const __bf16* vp = qkv + (size_t)(b * S_ + idxs[a]) * TRI_ + 2 * DIM_ + h * HD_ + d0;
        bf16x8 vv = *(const bf16x8*)vp;
        #pragma unroll
        for (int k = 0; k < 8; ++k) o[k] += p[a] * (float)vv[k];
    }
    bf16x8 ov;
    #pragma unroll
    for (int k = 0; k < 8; ++k) ov[k] = (__bf16)(o[k] * inv);
    *(bf16x8*)(attn_out + (size_t)(b * S_ + s) * DIM_ + h * HD_ + d0) = ov;
}

// ----------------------------------------------------------------------- launcher
extern "C" void kernel_launch(void* const* d_in, const int* in_sizes, int n_in,
                              void* d_out, int out_size, void* d_ws, size_t ws_size,
                              hipStream_t stream) {
    const float* x    = (const float*)d_in[0];
    const float* Wqkv = (const float*)d_in[1];
    const float* bqkv = (const float*)d_in[2];
    const float* Wout = (const float*)d_in[3];
    const float* bout = (const float*)d_in[4];
    const float* gsc  = (const float*)d_in[5];
    float* out = (float*)d_out;

    char* ws = (char*)d_ws;
    __bf16* x_bf   = (__bf16*)(ws);
    __bf16* WqkvT  = (__bf16*)(ws + 12582912);
    __bf16* WoutT  = (__bf16*)(ws + 12582912 + 14155776);
    __bf16* qkv    = (__bf16*)(ws + 12582912 + 14155776 + 4718592);
    __bf16* attn   = (__bf16*)(ws + 12582912 + 14155776 + 4718592 + 37748736);

    // prep: transposes + cvt (one launch)
    {
        int nblk = (TRI_ / 64) * (DIM_ / 64) + (DIM_ / 64) * (DIM_ / 64)
                 + (M_ * DIM_) / 1024;
        prep<<<nblk, 256, 0, stream>>>(Wqkv, WqkvT, Wout, WoutT, x, x_bf);
    }

    // QKV GEMM: 128x192 tiles -> 768 blocks (3.0/CU)
    gemm_qkv<<<(M_ / 128) * (TRI_ / 192), 256, 0, stream>>>(
        x_bf, WqkvT, bqkv, qkv, M_, TRI_, DIM_);

    // anchor attention
    anchor_attn<<<B_ * S_, 192, 0, stream>>>(qkv, gsc, attn);

    // out GEMM: 128x128 tiles, BK=128 -> 384 blocks
    gemm_out<<<(M_ / 128) * (DIM_ / 128), 256, 0, stream>>>(
        attn, WoutT, bout, out, M_, DIM_, DIM_);
}

// Round 8
// 229.849 us; speedup vs baseline: 1.0994x; 1.0010x over previous
//
#include <hip/hip_runtime.h>
#include <hip/hip_bf16.h>
#include <cstdint>
#include <math.h>

#define B_    2
#define S_    2048
#define DIM_  1536
#define H_    12
#define HD_   128
#define TRI_  4608   // 3*DIM
#define M_    4096   // B*S

typedef __attribute__((ext_vector_type(8)))  __bf16 bf16x8;
typedef __attribute__((ext_vector_type(4)))  __bf16 bf16x4;
typedef __attribute__((ext_vector_type(4)))  float  floatx4;
typedef __attribute__((ext_vector_type(16))) float  floatx16;

typedef __attribute__((address_space(3))) uint8_t       lds_u8;
typedef const __attribute__((address_space(1))) uint8_t glob_u8;

// ---------------- prep: W1/W2 transpose+cvt, x cvt — one launch
__global__ __launch_bounds__(256) void prep(const float* __restrict__ W1,
                                            __bf16* __restrict__ O1,
                                            const float* __restrict__ W2,
                                            __bf16* __restrict__ O2,
                                            const float* __restrict__ x,
                                            __bf16* __restrict__ x_bf) {
    const int T1 = (TRI_ / 64) * (DIM_ / 64);   // 1728
    const int T2 = (DIM_ / 64) * (DIM_ / 64);   // 576
    int blk = blockIdx.x;
    const int t = threadIdx.x;

    if (blk >= T1 + T2) {                       // cvt x -> bf16
        blk -= T1 + T2;
        int i = blk * 256 + t;
        float4 v = ((const float4*)x)[i];
        bf16x4 o;
        o.x = (__bf16)v.x; o.y = (__bf16)v.y; o.z = (__bf16)v.z; o.w = (__bf16)v.w;
        *(bf16x4*)(x_bf + (size_t)i * 4) = o;
        return;
    }

    const float* in; __bf16* out; int R, C, c0, r0;
    if (blk < T1) {
        in = W1; out = O1; R = DIM_; C = TRI_;
        c0 = (blk % (TRI_ / 64)) * 64; r0 = (blk / (TRI_ / 64)) * 64;
    } else {
        blk -= T1;
        in = W2; out = O2; R = DIM_; C = DIM_;
        c0 = (blk % (DIM_ / 64)) * 64; r0 = (blk / (DIM_ / 64)) * 64;
    }
    __shared__ float tile[64][65];
    const int c4 = t & 15, r = t >> 4;
    #pragma unroll
    for (int i = 0; i < 64; i += 16) {
        float4 v = *(const float4*)&in[(size_t)(r0 + r + i) * C + c0 + c4 * 4];
        tile[r + i][c4 * 4 + 0] = v.x;
        tile[r + i][c4 * 4 + 1] = v.y;
        tile[r + i][c4 * 4 + 2] = v.z;
        tile[r + i][c4 * 4 + 3] = v.w;
    }
    __syncthreads();
    const int cc = t >> 2, ch = t & 3;
    #pragma unroll
    for (int cho = 0; cho < 8; cho += 4) {
        int chh = ch + cho;
        bf16x8 o;
        #pragma unroll
        for (int k = 0; k < 8; ++k) o[k] = (__bf16)tile[chh * 8 + k][cc];
        *(bf16x8*)&out[(size_t)(c0 + cc) * R + r0 + chh * 8] = o;
    }
}

// -------------------- QKV GEMM 128x192, BK=64, single-buffer, 32x32x16 MFMA
// 4 waves each 64x96 as 2x3 of 32x32 frags; same 3-bit XOR swizzle (0 conflicts)
__global__ __launch_bounds__(256, 3) void gemm_qkv(const __bf16* __restrict__ A,
                                                   const __bf16* __restrict__ Bt,
                                                   const float*  __restrict__ bias,
                                                   __bf16* __restrict__ Cout,
                                                   int Mdim, int Ndim, int Kdim) {
    __shared__ __align__(16) __bf16 sA[128 * 64];   // 16 KB
    __shared__ __align__(16) __bf16 sB[192 * 64];   // 24 KB

    const int ntiles = Ndim / 192;
    const int tile_n = blockIdx.x % ntiles;
    const int tile_m = blockIdx.x / ntiles;
    const int m0 = tile_m << 7, n0 = tile_n * 192;

    const int tid  = threadIdx.x;
    const int lane = tid & 63;
    const int wave = tid >> 6;
    const int wm = (wave >> 1) * 64;
    const int wn = (wave & 1) * 96;

    floatx16 acc[2][3] = {};

    const int lr8 = lane >> 3;                  // staging row within 8-row group
    const int swz = (((lane & 7) ^ lr8) * 8);   // staging source chunk (swizzled)

    const int m32  = lane & 31;                 // MFMA row/col within 32
    const int half = lane >> 5;                 // k-half selector
    const int lx7  = lane & 7;                  // row&7 for frag reads (rows ≡ lane mod 8)

    for (int k0 = 0; k0 < Kdim; k0 += 64) {
        #pragma unroll
        for (int c = 0; c < 4; ++c) {
            int r0 = wave * 32 + c * 8;
            const __bf16* ga = A + (size_t)(m0 + r0 + lr8) * Kdim + k0 + swz;
            __builtin_amdgcn_global_load_lds((glob_u8*)ga, (lds_u8*)&sA[r0 * 64], 16, 0, 0);
        }
        #pragma unroll
        for (int c = 0; c < 6; ++c) {
            int r0 = wave * 48 + c * 8;
            const __bf16* gb = Bt + (size_t)(n0 + r0 + lr8) * Kdim + k0 + swz;
            __builtin_amdgcn_global_load_lds((glob_u8*)gb, (lds_u8*)&sB[r0 * 64], 16, 0, 0);
        }
        __syncthreads();

        #pragma unroll
        for (int ks = 0; ks < 4; ++ks) {        // 4 k-steps of 16
            const int ko = (((ks * 2 + half) ^ lx7) * 8);
            bf16x8 af[2], bfr[3];
            #pragma unroll
            for (int i = 0; i < 2; ++i)
                af[i] = *(const bf16x8*)&sA[(wm + i * 32 + m32) * 64 + ko];
            #pragma unroll
            for (int j = 0; j < 3; ++j)
                bfr[j] = *(const bf16x8*)&sB[(wn + j * 32 + m32) * 64 + ko];
            #pragma unroll
            for (int i = 0; i < 2; ++i)
                #pragma unroll
                for (int j = 0; j < 3; ++j)
                    acc[i][j] = __builtin_amdgcn_mfma_f32_32x32x16_bf16(af[i], bfr[j], acc[i][j], 0, 0, 0);
        }
        __syncthreads();
    }

    // C/D layout (m74/m101): col = lane&31, row = (reg&3) + 8*(reg>>2) + 4*(lane>>5)
    #pragma unroll
    for (int j = 0; j < 3; ++j) {
        int gc = n0 + wn + j * 32 + m32;
        float bv = bias[gc];
        #pragma unroll
        for (int i = 0; i < 2; ++i) {
            #pragma unroll
            for (int r = 0; r < 16; ++r) {
                int gr = m0 + wm + i * 32 + (r & 3) + 8 * (r >> 2) + 4 * half;
                Cout[(size_t)gr * Ndim + gc] = (__bf16)(acc[i][j][r] + bv);
            }
        }
    }
}

// ---------------- out GEMM: 128x128 tile, BK=128, single-buffer, 12 K-iters
// 64 KB LDS; 4-bit XOR swizzle for 256B rows (16 chunks of 16B)
__global__ __launch_bounds__(256) void gemm_out(const __bf16* __restrict__ A,
                                                const __bf16* __restrict__ Bt,
                                                const float*  __restrict__ bias,
                                                float* __restrict__ Cout,
                                                int Mdim, int Ndim, int Kdim) {
    __shared__ __align__(16) __bf16 sA[128 * 128];   // 32 KB
    __shared__ __align__(16) __bf16 sB[128 * 128];   // 32 KB

    const int ntiles = Ndim >> 7;
    const int tile_n = blockIdx.x % ntiles;
    const int tile_m = blockIdx.x / ntiles;
    const int m0 = tile_m << 7, n0 = tile_n << 7;

    const int tid  = threadIdx.x;
    const int lane = tid & 63;
    const int wave = tid >> 6;
    const int wm = (wave >> 1) * 64;
    const int wn = (wave & 1) * 64;

    floatx4 acc[4][4] = {};

    const int lr4 = lane >> 4;          // 0..3 : row within 4-row DMA group
    const int lc  = lane & 15;          // 16B-chunk slot
    int swz[4];
    #pragma unroll
    for (int v = 0; v < 4; ++v) swz[v] = (lc ^ (v * 4 + lr4)) * 8;  // elems

    const int row  = lane & 15;
    const int quad = lane >> 4;

    for (int k0 = 0; k0 < Kdim; k0 += 128) {
        #pragma unroll
        for (int c = 0; c < 8; ++c) {
            int r0 = wave * 32 + c * 4;          // wave-uniform base row
            const __bf16* ga = A + (size_t)(m0 + r0 + lr4) * Kdim + k0 + swz[c & 3];
            __builtin_amdgcn_global_load_lds((glob_u8*)ga, (lds_u8*)&sA[r0 * 128], 16, 0, 0);
            const __bf16* gb = Bt + (size_t)(n0 + r0 + lr4) * Kdim + k0 + swz[c & 3];
            __builtin_amdgcn_global_load_lds((glob_u8*)gb, (lds_u8*)&sB[r0 * 128], 16, 0, 0);
        }
        __syncthreads();

        #pragma unroll
        for (int ks = 0; ks < 4; ++ks) {
            const int ck = ((ks * 4 + quad) ^ row) * 8;
            bf16x8 af[4], bfr[4];
            #pragma unroll
            for (int i = 0; i < 4; ++i) {
                af[i]  = *(const bf16x8*)&sA[(wm + i * 16 + row) * 128 + ck];
                bfr[i] = *(const bf16x8*)&sB[(wn + i * 16 + row) * 128 + ck];
            }
            #pragma unroll
            for (int i = 0; i < 4; ++i)
                #pragma unroll
                for (int j = 0; j < 4; ++j)
                    acc[i][j] = __builtin_amdgcn_mfma_f32_16x16x32_bf16(af[i], bfr[j], acc[i][j], 0, 0, 0);
        }
        __syncthreads();
    }

    #pragma unroll
    for (int j = 0; j < 4; ++j) {
        int gc = n0 + wn + j * 16 + row;
        float bv = bias[gc];
        #pragma unroll
        for (int i = 0; i < 4; ++i) {
            #pragma unroll
            for (int r = 0; r < 4; ++r) {
                int gr = m0 + wm + i * 16 + quad * 4 + r;
                Cout[(size_t)gr * Ndim + gc] = acc[i][j][r] + bv;
            }
        }
    }
}

// ------------------------------------------------------------------ anchor attention
__global__ __launch_bounds__(192) void anchor_attn(const __bf16* __restrict__ qkv,
                                                   const float* __restrict__ group_scale,
                                                   __bf16* __restrict__ attn_out) {
    const int bs = blockIdx.x;
    const int b  = bs >> 11;
    const int s  = bs & 2047;
    const int t  = threadIdx.x;
    const int h  = t >> 4;
    const int tt = t & 15;
    const int d0 = tt * 8;

    float g0 = group_scale[0], g1 = group_scale[1], g2 = group_scale[2];
    float gm = fmaxf(g0, fmaxf(g1, g2));
    float e0 = __expf(g0 - gm), e1 = __expf(g1 - gm), e2 = __expf(g2 - gm);
    float ls = __logf(e0 + e1 + e2);
    float lw0 = g0 - gm - ls, lw1 = g1 - gm - ls, lw2 = g2 - gm - ls;

    const size_t rowbase = (size_t)(b * S_ + s) * TRI_ + h * HD_ + d0;
    bf16x8 qv = *(const bf16x8*)(qkv + rowbase);
    float q[8];
    #pragma unroll
    for (int k = 0; k < 8; ++k) q[k] = (float)qv[k];

    int idxs[12];
    const int offs[10] = {-3, -2, -1, 1, 2, 3, -10, -5, 5, 10};
    #pragma unroll
    for (int a = 0; a < 10; ++a) {
        int tgt = s + offs[a];
        idxs[a] = min(max(tgt, 0), S_ - 1);
    }
    idxs[10] = 0; idxs[11] = S_ - 1;

    const float scale = 0.08838834764831845f;
    float p[12];
    float mx = -1e30f;
    #pragma unroll
    for (int a = 0; a < 12; ++a) {
        const __bf16* kp = qkv + (size_t)(b * S_ + idxs[a]) * TRI_ + DIM_ + h * HD_ + d0;
        bf16x8 kv = *(const bf16x8*)kp;
        float d = 0.f;
        #pragma unroll
        for (int k = 0; k < 8; ++k) d += q[k] * (float)kv[k];
        d += __shfl_xor(d, 1); d += __shfl_xor(d, 2);
        d += __shfl_xor(d, 4); d += __shfl_xor(d, 8);
        float sc = d * scale + (a < 6 ? lw0 : (a < 10 ? lw1 : lw2));
        p[a] = sc;
        mx = fmaxf(mx, sc);
    }
    float l = 0.f;
    #pragma unroll
    for (int a = 0; a < 12; ++a) { p[a] = __expf(p[a] - mx); l += p[a]; }
    float inv = 1.0f / l;

    float o[8] = {};
    #pragma unroll
    for (int a = 0; a < 12; ++a) {
        const __bf16* vp = qkv + (size_t)(b * S_ + idxs[a]) * TRI_ + 2 * DIM_ + h * HD_ + d0;
        bf16x8 vv = *(const bf16x8*)vp;
        #pragma unroll
        for (int k = 0; k < 8; ++k) o[k] += p[a] * (float)vv[k];
    }
    bf16x8 ov;
    #pragma unroll
    for (int k = 0; k < 8; ++k) ov[k] = (__bf16)(o[k] * inv);
    *(bf16x8*)(attn_out + (size_t)(b * S_ + s) * DIM_ + h * HD_ + d0) = ov;
}

// ----------------------------------------------------------------------- launcher
extern "C" void kernel_launch(void* const* d_in, const int* in_sizes, int n_in,
                              void* d_out, int out_size, void* d_ws, size_t ws_size,
                              hipStream_t stream) {
    const float* x    = (const float*)d_in[0];
    const float* Wqkv = (const float*)d_in[1];
    const float* bqkv = (const float*)d_in[2];
    const float* Wout = (const float*)d_in[3];
    const float* bout = (const float*)d_in[4];
    const float* gsc  = (const float*)d_in[5];
    float* out = (float*)d_out;

    char* ws = (char*)d_ws;
    __bf16* x_bf   = (__bf16*)(ws);
    __bf16* WqkvT  = (__bf16*)(ws + 12582912);
    __bf16* WoutT  = (__bf16*)(ws + 12582912 + 14155776);
    __bf16* qkv    = (__bf16*)(ws + 12582912 + 14155776 + 4718592);
    __bf16* attn   = (__bf16*)(ws + 12582912 + 14155776 + 4718592 + 37748736);

    // prep: transposes + cvt (one launch)
    {
        int nblk = (TRI_ / 64) * (DIM_ / 64) + (DIM_ / 64) * (DIM_ / 64)
                 + (M_ * DIM_) / 1024;
        prep<<<nblk, 256, 0, stream>>>(Wqkv, WqkvT, Wout, WoutT, x, x_bf);
    }

    // QKV GEMM: 128x192 tiles -> 768 blocks (3.0/CU), 32x32x16 MFMA
    gemm_qkv<<<(M_ / 128) * (TRI_ / 192), 256, 0, stream>>>(
        x_bf, WqkvT, bqkv, qkv, M_, TRI_, DIM_);

    // anchor attention
    anchor_attn<<<B_ * S_, 192, 0, stream>>>(qkv, gsc, attn);

    // out GEMM: 128x128 tiles, BK=128 -> 384 blocks
    gemm_out<<<(M_ / 128) * (DIM_ / 128), 256, 0, stream>>>(
        attn, WoutT, bout, out, M_, DIM_, DIM_);
}